// Round 5
// baseline (355.820 us; speedup 1.0000x reference)
//
#include <hip/hip_runtime.h>
#include <hip/hip_bf16.h>

typedef unsigned short u16;
typedef unsigned int   u32;
typedef __attribute__((ext_vector_type(8))) __bf16 bf16x8;
typedef __attribute__((ext_vector_type(2))) __bf16 bf16x2;
typedef __attribute__((ext_vector_type(8))) u16    ushort8v;
typedef __attribute__((ext_vector_type(2))) float  f32x2;
typedef __attribute__((ext_vector_type(4))) float  floatx4;

#define EMBED 1024
#define SEQ   2048
#define BATCH 4
#define NH    16
#define DKH   64
#define BHN   (BATCH*NH)              // 64
#define ZSTRIDE ((size_t)BHN*SEQ*DKH) // elements per Q/K/V plane

// ---- fp32 -> bf16 RTNE ----
__device__ __forceinline__ u16 f2bf(float f){
  union { float f; unsigned u; } v; v.f = f;
  unsigned r = (v.u + 0x7FFFu + ((v.u >> 16) & 1u)) >> 16;
  return (u16)r;
}
// packed pair via v_cvt_pk_bf16_f32
__device__ __forceinline__ u32 pk2(float a, float b){
  f32x2 v = {a, b};
  return __builtin_bit_cast(u32, __builtin_convertvector(v, bf16x2));
}

__device__ __forceinline__ bf16x8 ld_frag(const u16* p){
  return __builtin_bit_cast(bf16x8, *(const ushort8v*)p);
}

__device__ __forceinline__ floatx4 mfma16(bf16x8 a, bf16x8 b, floatx4 c){
  return __builtin_amdgcn_mfma_f32_16x16x32_bf16(a, b, c, 0, 0, 0);
}

// async global->LDS, 16B per lane; LDS dst must be uniform_base + lane*16
__device__ __forceinline__ void gl_lds16(const u16* g, u16* l){
  __builtin_amdgcn_global_load_lds((const __attribute__((address_space(1))) void*)g,
                                   (__attribute__((address_space(3))) void*)l,
                                   16, 0, 0);
}

// =================== fused cast kernel ===================
__global__ __launch_bounds__(256) void cvt_all(const float* __restrict__ x,
    const float* __restrict__ wq, const float* __restrict__ wk,
    const float* __restrict__ wv, const float* __restrict__ wo,
    u16* __restrict__ Xb, u16* __restrict__ Wqb, u16* __restrict__ Wkb,
    u16* __restrict__ Wvb, u16* __restrict__ Wob){
  int b = blockIdx.x;
  const float* src; u16* dst; int i;
  if (b < 8192){ src = x; dst = Xb; i = b*256 + threadIdx.x; }
  else {
    int k = (b - 8192) >> 10, r = (b - 8192) & 1023;
    src = (k==0) ? wq : (k==1) ? wk : (k==2) ? wv : wo;
    dst = (k==0) ? Wqb : (k==1) ? Wkb : (k==2) ? Wvb : Wob;
    i = r*256 + threadIdx.x;
  }
  float4 v = ((const float4*)src)[i];
  ushort4 o;
  o.x = f2bf(v.x); o.y = f2bf(v.y); o.z = f2bf(v.z); o.w = f2bf(v.w);
  ((ushort4*)dst)[i] = o;
}

// =================== GEMM core (m97 structure) ===================
__device__ __forceinline__ void gemm_core(const u16* Abase, const u16* Bbase,
                                          u16* As, u16* Bs, floatx4 acc[4][4]){
  const int tid  = threadIdx.x;
  const int lane = tid & 63, w = tid >> 6;
  const int lm   = lane & 15, quad = lane >> 4;
  const int wm   = (w & 1) * 64, wn = (w >> 1) * 64;

  #pragma unroll
  for (int mi = 0; mi < 4; ++mi)
    #pragma unroll
    for (int ni = 0; ni < 4; ++ni)
      acc[mi][ni] = (floatx4){0.f, 0.f, 0.f, 0.f};

  for (int kt = 0; kt < EMBED/32; ++kt){
    const int k0 = kt * 32;
    __syncthreads();
    #pragma unroll
    for (int r = 0; r < 2; ++r){
      int i = r*256 + tid;
      int row = i >> 2, kc = i & 3;
      gl_lds16(Abase + (size_t)row*EMBED + k0 + kc*8, As + i*8);
      gl_lds16(Bbase + (size_t)row*EMBED + k0 + kc*8, Bs + i*8);
    }
    __syncthreads();
    bf16x8 af[4], bf[4];
    #pragma unroll
    for (int mi = 0; mi < 4; ++mi)
      af[mi] = ld_frag(&As[(wm + mi*16 + lm)*32 + quad*8]);
    #pragma unroll
    for (int ni = 0; ni < 4; ++ni)
      bf[ni] = ld_frag(&Bs[(wn + ni*16 + lm)*32 + quad*8]);
    #pragma unroll
    for (int mi = 0; mi < 4; ++mi)
      #pragma unroll
      for (int ni = 0; ni < 4; ++ni)
        acc[mi][ni] = mfma16(af[mi], bf[ni], acc[mi][ni]);
  }
}

// QKV projection. z=0: Q (scaled by 0.125*log2e), z=1: K — layout [bh][s][d].
// z=2: V — layout [bh][d][s] (plain; attn reads V fragments direct from L2).
#define QSCALE 0.1803368801111204f   // 0.125 * log2(e)
__global__ __launch_bounds__(256) void gemm_qkv(const u16* __restrict__ X,
    const u16* __restrict__ Wq, const u16* __restrict__ Wk, const u16* __restrict__ Wv,
    u16* __restrict__ QKV){
  __shared__ __attribute__((aligned(16))) u16 As[128*32];
  __shared__ __attribute__((aligned(16))) u16 Bs[128*32];
  const int z  = blockIdx.z;
  const u16* W = (z == 0) ? Wq : (z == 1) ? Wk : Wv;
  const int m0 = blockIdx.y * 128, n0 = blockIdx.x * 128;
  floatx4 acc[4][4];
  gemm_core(X + (size_t)m0*EMBED, W + (size_t)n0*EMBED, As, Bs, acc);

  const int tid = threadIdx.x, lane = tid & 63, w = tid >> 6;
  const int lm = lane & 15, quad = lane >> 4;
  const int wm = (w & 1) * 64, wn = (w >> 1) * 64;
  u16* outz = QKV + (size_t)z * ZSTRIDE;

  if (z == 2){
    #pragma unroll
    for (int mi = 0; mi < 4; ++mi)
      #pragma unroll
      for (int ni = 0; ni < 4; ++ni){
        int mbase = m0 + wm + mi*16 + quad*4;       // 4 consecutive s
        int n = n0 + wn + ni*16 + lm;
        int b = mbase >> 11, sb = mbase & 2047;
        int h = n >> 6, d = n & 63;
        u16* dst = outz + (((size_t)(b*NH + h))*DKH + d)*SEQ + sb;
        uint2 pv;
        pv.x = pk2(acc[mi][ni][0], acc[mi][ni][1]);
        pv.y = pk2(acc[mi][ni][2], acc[mi][ni][3]);
        *reinterpret_cast<uint2*>(dst) = pv;
      }
  } else {
    const float scale = (z == 0) ? QSCALE : 1.0f;
    #pragma unroll
    for (int mi = 0; mi < 4; ++mi)
      #pragma unroll
      for (int ni = 0; ni < 4; ++ni)
        #pragma unroll
        for (int r = 0; r < 4; ++r){
          int m = m0 + wm + mi*16 + quad*4 + r;
          int n = n0 + wn + ni*16 + lm;
          int b = m >> 11, s = m & 2047, h = n >> 6, d = n & 63;
          outz[(((size_t)(b*NH + h))*SEQ + s)*DKH + d] = f2bf(acc[mi][ni][r] * scale);
        }
  }
}

// Final: out = Attn * Wo^T, fp32 out [b*s][e]
__global__ __launch_bounds__(256) void gemm_out(const u16* __restrict__ A,
    const u16* __restrict__ W, float* __restrict__ C){
  __shared__ __attribute__((aligned(16))) u16 As[128*32];
  __shared__ __attribute__((aligned(16))) u16 Bs[128*32];
  const int m0 = blockIdx.y * 128, n0 = blockIdx.x * 128;
  floatx4 acc[4][4];
  gemm_core(A + (size_t)m0*EMBED, W + (size_t)n0*EMBED, As, Bs, acc);

  const int tid = threadIdx.x, lane = tid & 63, w = tid >> 6;
  const int lm = lane & 15, quad = lane >> 4;
  const int wm = (w & 1) * 64, wn = (w >> 1) * 64;
  #pragma unroll
  for (int mi = 0; mi < 4; ++mi)
    #pragma unroll
    for (int ni = 0; ni < 4; ++ni)
      #pragma unroll
      for (int r = 0; r < 4; ++r){
        int m = m0 + wm + mi*16 + quad*4 + r;
        int n = n0 + wn + ni*16 + lm;
        C[(size_t)m*EMBED + n] = acc[mi][ni][r];
      }
}

// =================== fused attention ===================
// grid (64, 16): x = bh (so blocks sharing K/V land on the same XCD via %8),
// y = q-block of 128 rows. 4 waves x 32 q (2 q-tiles). Keys chunked by 64.
// K double-buffered via global_load_lds; V fragments read DIRECT from global
// (L2-resident per XCD): 16B per lane, no LDS staging. LDS = 35 KB ->
// 4 blocks/CU = 16 waves/CU (launch_bounds pins VGPR <= 128).
#define KSS 520
#define PSS 72
__global__ __launch_bounds__(256, 4) void attn_kernel(const u16* __restrict__ QKV,
                                                      u16* __restrict__ Out){
  __shared__ __attribute__((aligned(16))) u16 Ks[2][8*KSS];   // 16.6 KB
  __shared__ __attribute__((aligned(16))) u16 Ps[128*PSS];    // 18.4 KB

  const int tid = threadIdx.x, lane = tid & 63, w = tid >> 6;
  const int lm = lane & 15, quad = lane >> 4;
  const int bh = blockIdx.x;
  const int q0 = blockIdx.y * 128;
  const u16* Qh = QKV + (size_t)bh * SEQ * DKH;
  const u16* Kh = QKV + ZSTRIDE + (size_t)bh * SEQ * DKH;
  const u16* Vh = QKV + 2*ZSTRIDE + (size_t)bh * DKH * SEQ;  // [d][s]

  const int sK = tid & 63, cK = tid >> 6;            // K staging coords

  // Q fragments: B-operand layout (n=q, k=d contiguous)
  bf16x8 qf[2][2];
  #pragma unroll
  for (int qt = 0; qt < 2; ++qt)
    #pragma unroll
    for (int st = 0; st < 2; ++st)
      qf[qt][st] = ld_frag(Qh + (size_t)(q0 + w*32 + qt*16 + lm)*DKH + st*32 + quad*8);

  ushort8v onesu;
  #pragma unroll
  for (int e = 0; e < 8; ++e) onesu[e] = 0x3F80;   // bf16 1.0
  const bf16x8 ones = __builtin_bit_cast(bf16x8, onesu);

  floatx4 o[2][4], lac[2];
  #pragma unroll
  for (int qt = 0; qt < 2; ++qt){
    lac[qt] = (floatx4){0.f, 0.f, 0.f, 0.f};
    #pragma unroll
    for (int dt = 0; dt < 4; ++dt) o[qt][dt] = (floatx4){0.f, 0.f, 0.f, 0.f};
  }

  // prologue: stage K kt=0 into buffer 0
  gl_lds16(Kh + (size_t)sK*DKH + cK*8,     Ks[0] + cK*KSS + sK*8);
  gl_lds16(Kh + (size_t)sK*DKH + (cK+4)*8, Ks[0] + (cK+4)*KSS + sK*8);

  for (int kt = 0; kt < SEQ/64; ++kt){
    const int cur = kt & 1;
    const int sk0 = kt * 64;
    // one barrier per kt: drains vmcnt (Ks[cur] DMA done) + all waves done
    // reading Ks[cur^1] in iter kt-1 -> safe to overwrite it below.
    __syncthreads();
    if (kt + 1 < SEQ/64){
      const int nk0 = (kt + 1) * 64;
      gl_lds16(Kh + (size_t)(nk0 + sK)*DKH + cK*8,     Ks[cur^1] + cK*KSS + sK*8);
      gl_lds16(Kh + (size_t)(nk0 + sK)*DKH + (cK+4)*8, Ks[cur^1] + (cK+4)*KSS + sK*8);
    }
    const u16* Kc = Ks[cur];

    // V fragments for st=0 issued early: latency overlaps the S/exp phase
    bf16x8 vb0[4];
    #pragma unroll
    for (int dt = 0; dt < 4; ++dt)
      vb0[dt] = ld_frag(Vh + (size_t)(dt*16 + lm)*SEQ + sk0 + quad*8);

    // S^T tiles: A=K (m=key), B=Q (n=q); exp2 + packed P store
    #pragma unroll
    for (int t = 0; t < 4; ++t){
      bf16x8 kf0 = ld_frag(&Kc[quad*KSS     + (t*16 + lm)*8]);
      bf16x8 kf1 = ld_frag(&Kc[(quad+4)*KSS + (t*16 + lm)*8]);
      floatx4 s0 = (floatx4){0.f,0.f,0.f,0.f}, s1 = s0;
      s0 = mfma16(kf0, qf[0][0], s0); s0 = mfma16(kf1, qf[0][1], s0);
      s1 = mfma16(kf0, qf[1][0], s1); s1 = mfma16(kf1, qf[1][1], s1);
      uint2 p0, p1;
      p0.x = pk2(__builtin_amdgcn_exp2f(s0[0]), __builtin_amdgcn_exp2f(s0[1]));
      p0.y = pk2(__builtin_amdgcn_exp2f(s0[2]), __builtin_amdgcn_exp2f(s0[3]));
      p1.x = pk2(__builtin_amdgcn_exp2f(s1[0]), __builtin_amdgcn_exp2f(s1[1]));
      p1.y = pk2(__builtin_amdgcn_exp2f(s1[2]), __builtin_amdgcn_exp2f(s1[3]));
      *reinterpret_cast<uint2*>(&Ps[(w*32      + lm)*PSS + t*16 + quad*4]) = p0;
      *reinterpret_cast<uint2*>(&Ps[(w*32 + 16 + lm)*PSS + t*16 + quad*4]) = p1;
    }
    asm volatile("" ::: "memory");      // P writes before P reads (wave-private rows)

    // O += P V ;  l += P 1   (V frags direct from global/L2)
    #pragma unroll
    for (int st = 0; st < 2; ++st){
      bf16x8 vb[4];
      if (st == 0){
        #pragma unroll
        for (int dt = 0; dt < 4; ++dt) vb[dt] = vb0[dt];
      } else {
        #pragma unroll
        for (int dt = 0; dt < 4; ++dt)
          vb[dt] = ld_frag(Vh + (size_t)(dt*16 + lm)*SEQ + sk0 + 32 + quad*8);
      }
      bf16x8 pa0 = ld_frag(&Ps[(w*32      + lm)*PSS + st*32 + quad*8]);
      bf16x8 pa1 = ld_frag(&Ps[(w*32 + 16 + lm)*PSS + st*32 + quad*8]);
      lac[0] = mfma16(pa0, ones, lac[0]);
      lac[1] = mfma16(pa1, ones, lac[1]);
      #pragma unroll
      for (int dt = 0; dt < 4; ++dt){
        o[0][dt] = mfma16(pa0, vb[dt], o[0][dt]);
        o[1][dt] = mfma16(pa1, vb[dt], o[1][dt]);
      }
    }
    asm volatile("" ::: "memory");
  }

  const int bI = bh >> 4, h = bh & 15;
  #pragma unroll
  for (int qt = 0; qt < 2; ++qt){
    floatx4 inv;
    #pragma unroll
    for (int r = 0; r < 4; ++r) inv[r] = __builtin_amdgcn_rcpf(lac[qt][r]);
    #pragma unroll
    for (int dt = 0; dt < 4; ++dt)
      #pragma unroll
      for (int r = 0; r < 4; ++r){
        int s = q0 + w*32 + qt*16 + quad*4 + r;
        Out[((size_t)(bI*SEQ + s))*EMBED + h*DKH + dt*16 + lm] = f2bf(o[qt][dt][r] * inv[r]);
      }
  }
}

// =================== launch ===================
extern "C" void kernel_launch(void* const* d_in, const int* in_sizes, int n_in,
                              void* d_out, int out_size, void* d_ws, size_t ws_size,
                              hipStream_t stream){
  const float* x  = (const float*)d_in[0];
  const float* Wq = (const float*)d_in[1];
  const float* Wk = (const float*)d_in[2];
  const float* Wv = (const float*)d_in[3];
  const float* Wo = (const float*)d_in[4];
  float* out = (float*)d_out;

  char* ws = (char*)d_ws;
  u16* Xb  = (u16*)ws;                          // 16 MB
  u16* Wqb = (u16*)(ws + (size_t)16777216);     // 4 x 2 MB
  u16* Wkb = Wqb + 1048576;
  u16* Wvb = Wkb + 1048576;
  u16* Wob = Wvb + 1048576;
  u16* QKV = (u16*)(ws + (size_t)25165824);     // 3 x 16.78 MB
  u16* At  = (u16*)(ws + (size_t)75497472);     // 16 MB

  cvt_all<<<12288, 256, 0, stream>>>(x, Wq, Wk, Wv, Wo, Xb, Wqb, Wkb, Wvb, Wob);
  gemm_qkv<<<dim3(8, 64, 3), 256, 0, stream>>>(Xb, Wqb, Wkb, Wvb, QKV);
  attn_kernel<<<dim3(64, 16), 256, 0, stream>>>(QKV, At);
  gemm_out<<<dim3(8, 64), 256, 0, stream>>>(At, Wob, out);
}

// Round 6
// 284.773 us; speedup vs baseline: 1.2495x; 1.2495x over previous
//
#include <hip/hip_runtime.h>
#include <hip/hip_bf16.h>

typedef unsigned short u16;
typedef unsigned int   u32;
typedef __attribute__((ext_vector_type(8))) __bf16 bf16x8;
typedef __attribute__((ext_vector_type(2))) __bf16 bf16x2;
typedef __attribute__((ext_vector_type(8))) u16    ushort8v;
typedef __attribute__((ext_vector_type(4))) short  short4v;
typedef __attribute__((ext_vector_type(2))) float  f32x2;
typedef __attribute__((ext_vector_type(4))) float  floatx4;

#define EMBED 1024
#define SEQ   2048
#define BATCH 4
#define NH    16
#define DKH   64
#define BHN   (BATCH*NH)              // 64
#define ZSTRIDE ((size_t)BHN*SEQ*DKH) // elements per Q/K/V plane

// ---- fp32 -> bf16 RTNE ----
__device__ __forceinline__ u16 f2bf(float f){
  union { float f; unsigned u; } v; v.f = f;
  unsigned r = (v.u + 0x7FFFu + ((v.u >> 16) & 1u)) >> 16;
  return (u16)r;
}
// packed pair via v_cvt_pk_bf16_f32
__device__ __forceinline__ u32 pk2(float a, float b){
  f32x2 v = {a, b};
  return __builtin_bit_cast(u32, __builtin_convertvector(v, bf16x2));
}

__device__ __forceinline__ bf16x8 ld_frag(const u16* p){
  return __builtin_bit_cast(bf16x8, *(const ushort8v*)p);
}

__device__ __forceinline__ floatx4 mfma16(bf16x8 a, bf16x8 b, floatx4 c){
  return __builtin_amdgcn_mfma_f32_16x16x32_bf16(a, b, c, 0, 0, 0);
}
// K=16 MFMA: A/B are 4 bf16 (2 VGPRs) — P-in-registers PV path
__device__ __forceinline__ floatx4 mfma_pv(short4v a, short4v b, floatx4 c){
  return __builtin_amdgcn_mfma_f32_16x16x16bf16_1k(a, b, c, 0, 0, 0);
}

// async global->LDS, 16B per lane; LDS dst must be uniform_base + lane*16
__device__ __forceinline__ void gl_lds16(const u16* g, u16* l){
  __builtin_amdgcn_global_load_lds((const __attribute__((address_space(1))) void*)g,
                                   (__attribute__((address_space(3))) void*)l,
                                   16, 0, 0);
}

// =================== fused cast kernel ===================
__global__ __launch_bounds__(256) void cvt_all(const float* __restrict__ x,
    const float* __restrict__ wq, const float* __restrict__ wk,
    const float* __restrict__ wv, const float* __restrict__ wo,
    u16* __restrict__ Xb, u16* __restrict__ Wqb, u16* __restrict__ Wkb,
    u16* __restrict__ Wvb, u16* __restrict__ Wob){
  int b = blockIdx.x;
  const float* src; u16* dst; int i;
  if (b < 8192){ src = x; dst = Xb; i = b*256 + threadIdx.x; }
  else {
    int k = (b - 8192) >> 10, r = (b - 8192) & 1023;
    src = (k==0) ? wq : (k==1) ? wk : (k==2) ? wv : wo;
    dst = (k==0) ? Wqb : (k==1) ? Wkb : (k==2) ? Wvb : Wob;
    i = r*256 + threadIdx.x;
  }
  float4 v = ((const float4*)src)[i];
  ushort4 o;
  o.x = f2bf(v.x); o.y = f2bf(v.y); o.z = f2bf(v.z); o.w = f2bf(v.w);
  ((ushort4*)dst)[i] = o;
}

// =================== GEMM core (m97 structure) ===================
__device__ __forceinline__ void gemm_core(const u16* Abase, const u16* Bbase,
                                          u16* As, u16* Bs, floatx4 acc[4][4]){
  const int tid  = threadIdx.x;
  const int lane = tid & 63, w = tid >> 6;
  const int lm   = lane & 15, quad = lane >> 4;
  const int wm   = (w & 1) * 64, wn = (w >> 1) * 64;

  #pragma unroll
  for (int mi = 0; mi < 4; ++mi)
    #pragma unroll
    for (int ni = 0; ni < 4; ++ni)
      acc[mi][ni] = (floatx4){0.f, 0.f, 0.f, 0.f};

  for (int kt = 0; kt < EMBED/32; ++kt){
    const int k0 = kt * 32;
    __syncthreads();
    #pragma unroll
    for (int r = 0; r < 2; ++r){
      int i = r*256 + tid;
      int row = i >> 2, kc = i & 3;
      gl_lds16(Abase + (size_t)row*EMBED + k0 + kc*8, As + i*8);
      gl_lds16(Bbase + (size_t)row*EMBED + k0 + kc*8, Bs + i*8);
    }
    __syncthreads();
    bf16x8 af[4], bf[4];
    #pragma unroll
    for (int mi = 0; mi < 4; ++mi)
      af[mi] = ld_frag(&As[(wm + mi*16 + lm)*32 + quad*8]);
    #pragma unroll
    for (int ni = 0; ni < 4; ++ni)
      bf[ni] = ld_frag(&Bs[(wn + ni*16 + lm)*32 + quad*8]);
    #pragma unroll
    for (int mi = 0; mi < 4; ++mi)
      #pragma unroll
      for (int ni = 0; ni < 4; ++ni)
        acc[mi][ni] = mfma16(af[mi], bf[ni], acc[mi][ni]);
  }
}

// QKV projection. z=0: Q (scaled by 0.125*log2e), z=1: K — layout [bh][s][d].
// z=2: V — layout [bh][d][s] plain (attn XOR-swizzles at the DMA source).
#define QSCALE 0.1803368801111204f   // 0.125 * log2(e)
__global__ __launch_bounds__(256) void gemm_qkv(const u16* __restrict__ X,
    const u16* __restrict__ Wq, const u16* __restrict__ Wk, const u16* __restrict__ Wv,
    u16* __restrict__ QKV){
  __shared__ __attribute__((aligned(16))) u16 As[128*32];
  __shared__ __attribute__((aligned(16))) u16 Bs[128*32];
  const int z  = blockIdx.z;
  const u16* W = (z == 0) ? Wq : (z == 1) ? Wk : Wv;
  const int m0 = blockIdx.y * 128, n0 = blockIdx.x * 128;
  floatx4 acc[4][4];
  gemm_core(X + (size_t)m0*EMBED, W + (size_t)n0*EMBED, As, Bs, acc);

  const int tid = threadIdx.x, lane = tid & 63, w = tid >> 6;
  const int lm = lane & 15, quad = lane >> 4;
  const int wm = (w & 1) * 64, wn = (w >> 1) * 64;
  u16* outz = QKV + (size_t)z * ZSTRIDE;

  if (z == 2){
    #pragma unroll
    for (int mi = 0; mi < 4; ++mi)
      #pragma unroll
      for (int ni = 0; ni < 4; ++ni){
        int mbase = m0 + wm + mi*16 + quad*4;       // 4 consecutive s
        int n = n0 + wn + ni*16 + lm;
        int b = mbase >> 11, sb = mbase & 2047;
        int h = n >> 6, d = n & 63;
        u16* dst = outz + (((size_t)(b*NH + h))*DKH + d)*SEQ + sb;
        uint2 pv;
        pv.x = pk2(acc[mi][ni][0], acc[mi][ni][1]);
        pv.y = pk2(acc[mi][ni][2], acc[mi][ni][3]);
        *reinterpret_cast<uint2*>(dst) = pv;
      }
  } else {
    const float scale = (z == 0) ? QSCALE : 1.0f;
    #pragma unroll
    for (int mi = 0; mi < 4; ++mi)
      #pragma unroll
      for (int ni = 0; ni < 4; ++ni)
        #pragma unroll
        for (int r = 0; r < 4; ++r){
          int m = m0 + wm + mi*16 + quad*4 + r;
          int n = n0 + wn + ni*16 + lm;
          int b = m >> 11, s = m & 2047, h = n >> 6, d = n & 63;
          outz[(((size_t)(b*NH + h))*SEQ + s)*DKH + d] = f2bf(acc[mi][ni][r] * scale);
        }
  }
}

// Final: out = Attn * Wo^T, fp32 out [b*s][e]
__global__ __launch_bounds__(256) void gemm_out(const u16* __restrict__ A,
    const u16* __restrict__ W, float* __restrict__ C){
  __shared__ __attribute__((aligned(16))) u16 As[128*32];
  __shared__ __attribute__((aligned(16))) u16 Bs[128*32];
  const int m0 = blockIdx.y * 128, n0 = blockIdx.x * 128;
  floatx4 acc[4][4];
  gemm_core(A + (size_t)m0*EMBED, W + (size_t)n0*EMBED, As, Bs, acc);

  const int tid = threadIdx.x, lane = tid & 63, w = tid >> 6;
  const int lm = lane & 15, quad = lane >> 4;
  const int wm = (w & 1) * 64, wn = (w >> 1) * 64;
  #pragma unroll
  for (int mi = 0; mi < 4; ++mi)
    #pragma unroll
    for (int ni = 0; ni < 4; ++ni)
      #pragma unroll
      for (int r = 0; r < 4; ++r){
        int m = m0 + wm + mi*16 + quad*4 + r;
        int n = n0 + wn + ni*16 + lm;
        C[(size_t)m*EMBED + n] = acc[mi][ni][r];
      }
}

// =================== fused attention (P stays in registers) ===================
// grid (64, 16): x = bh (XCD-local L2 reuse of K/V), y = q-block of 128 rows.
// 4 waves x 32 q (2 q-tiles). Keys chunked by 64, K/V double-buffered DMA,
// single barrier per kt. S^T C-layout (q=lm, key=quad*4+reg) is EXACTLY the
// A-operand layout of mfma_f32_16x16x16_bf16 -> exp'd P packs straight into
// PV A-frags: no P LDS round-trip, no fence. V staged [d][key] stride 64 with
// XOR swizzle (g^(d&7)) applied at the DMA *source* so b64 B-frag reads are
// conflict-free while DMA dst stays linear. LDS = 33 KB -> 4 blocks/CU.
#define KSS 520
__global__ __launch_bounds__(256, 4) void attn_kernel(const u16* __restrict__ QKV,
                                                      u16* __restrict__ Out){
  __shared__ __attribute__((aligned(16))) u16 Ks[2][8*KSS];   // 16.6 KB
  __shared__ __attribute__((aligned(16))) u16 Vs[2][64*64];   // 16.4 KB

  const int tid = threadIdx.x, lane = tid & 63, w = tid >> 6;
  const int lm = lane & 15, quad = lane >> 4;
  const int bh = blockIdx.x;
  const int q0 = blockIdx.y * 128;
  const u16* Qh = QKV + (size_t)bh * SEQ * DKH;
  const u16* Kh = QKV + ZSTRIDE + (size_t)bh * SEQ * DKH;
  const u16* Vh = QKV + 2*ZSTRIDE + (size_t)bh * DKH * SEQ;  // [d][s] plain

  // K staging coords (chunk c = r*4 + cK is wave-uniform)
  const int sK = tid & 63, cK = tid >> 6;
  // V staging coords: i = r*256+tid -> d = i>>3 (r=1: d+32), group g = i&7.
  // XOR swizzle at source: src key-group = g ^ (d&7); (d+32)&7 == d&7.
  const int dV = tid >> 3, gV = tid & 7;
  const size_t vsrc0 = (size_t)dV * SEQ + ((gV ^ (dV & 7)) * 8);
  const size_t vsrc1 = vsrc0 + (size_t)32 * SEQ;

  // Q fragments: B-operand layout (n=q, k=d contiguous)
  bf16x8 qf[2][2];
  #pragma unroll
  for (int qt = 0; qt < 2; ++qt)
    #pragma unroll
    for (int st = 0; st < 2; ++st)
      qf[qt][st] = ld_frag(Qh + (size_t)(q0 + w*32 + qt*16 + lm)*DKH + st*32 + quad*8);

  const short4v ones4 = {0x3F80, 0x3F80, 0x3F80, 0x3F80};   // bf16 1.0 x4

  floatx4 o[2][4], lac[2];
  #pragma unroll
  for (int qt = 0; qt < 2; ++qt){
    lac[qt] = (floatx4){0.f, 0.f, 0.f, 0.f};
    #pragma unroll
    for (int dt = 0; dt < 4; ++dt) o[qt][dt] = (floatx4){0.f, 0.f, 0.f, 0.f};
  }

  // prologue: stage kt=0 into buffer 0
  gl_lds16(Kh + (size_t)sK*DKH + cK*8,     Ks[0] + cK*KSS + sK*8);
  gl_lds16(Kh + (size_t)sK*DKH + (cK+4)*8, Ks[0] + (cK+4)*KSS + sK*8);
  gl_lds16(Vh + vsrc0,                     Vs[0] + tid*8);
  gl_lds16(Vh + vsrc1,                     Vs[0] + 2048 + tid*8);

  for (int kt = 0; kt < SEQ/64; ++kt){
    const int cur = kt & 1;
    // one barrier per kt: drains vmcnt (buf[cur] DMA done) + all waves done
    // reading buf[cur^1] in iter kt-1 -> safe to overwrite below.
    __syncthreads();
    if (kt + 1 < SEQ/64){
      const int nk0 = (kt + 1) * 64;
      gl_lds16(Kh + (size_t)(nk0 + sK)*DKH + cK*8,     Ks[cur^1] + cK*KSS + sK*8);
      gl_lds16(Kh + (size_t)(nk0 + sK)*DKH + (cK+4)*8, Ks[cur^1] + (cK+4)*KSS + sK*8);
      gl_lds16(Vh + vsrc0 + nk0,                       Vs[cur^1] + tid*8);
      gl_lds16(Vh + vsrc1 + nk0,                       Vs[cur^1] + 2048 + tid*8);
    }
    const u16* Kc = Ks[cur];
    const u16* Vc = Vs[cur];

    #pragma unroll
    for (int t = 0; t < 4; ++t){
      // S^T tile t: A=K (m=key t*16+lm fragment rows), B=Q (n=q)
      bf16x8 kf0 = ld_frag(&Kc[quad*KSS     + (t*16 + lm)*8]);
      bf16x8 kf1 = ld_frag(&Kc[(quad+4)*KSS + (t*16 + lm)*8]);
      short4v pf[2];
      #pragma unroll
      for (int qt = 0; qt < 2; ++qt){
        floatx4 s = (floatx4){0.f,0.f,0.f,0.f};
        s = mfma16(kf0, qf[qt][0], s);
        s = mfma16(kf1, qf[qt][1], s);
        uint2 p;
        p.x = pk2(__builtin_amdgcn_exp2f(s[0]), __builtin_amdgcn_exp2f(s[1]));
        p.y = pk2(__builtin_amdgcn_exp2f(s[2]), __builtin_amdgcn_exp2f(s[3]));
        pf[qt] = __builtin_bit_cast(short4v, p);   // A-frag: m=q(lm), k=key(quad*4+j)
      }
      // l += P·1
      lac[0] = mfma_pv(pf[0], ones4, lac[0]);
      lac[1] = mfma_pv(pf[1], ones4, lac[1]);
      // O += P·V : B-frag from swizzled Vs, b64 per (t,dt)
      const int cg = ((t*2 + (quad >> 1)) ^ (lm & 7)) * 8 + (quad & 1) * 4;
      #pragma unroll
      for (int dt = 0; dt < 4; ++dt){
        short4v vb = __builtin_bit_cast(short4v,
                        *(const uint2*)(Vc + (dt*16 + lm)*64 + cg));
        o[0][dt] = mfma_pv(pf[0], vb, o[0][dt]);
        o[1][dt] = mfma_pv(pf[1], vb, o[1][dt]);
      }
    }
  }

  const int bI = bh >> 4, h = bh & 15;
  #pragma unroll
  for (int qt = 0; qt < 2; ++qt){
    floatx4 inv;
    #pragma unroll
    for (int r = 0; r < 4; ++r) inv[r] = __builtin_amdgcn_rcpf(lac[qt][r]);
    #pragma unroll
    for (int dt = 0; dt < 4; ++dt)
      #pragma unroll
      for (int r = 0; r < 4; ++r){
        int s = q0 + w*32 + qt*16 + quad*4 + r;
        Out[((size_t)(bI*SEQ + s))*EMBED + h*DKH + dt*16 + lm] = f2bf(o[qt][dt][r] * inv[r]);
      }
  }
}

// =================== launch ===================
extern "C" void kernel_launch(void* const* d_in, const int* in_sizes, int n_in,
                              void* d_out, int out_size, void* d_ws, size_t ws_size,
                              hipStream_t stream){
  const float* x  = (const float*)d_in[0];
  const float* Wq = (const float*)d_in[1];
  const float* Wk = (const float*)d_in[2];
  const float* Wv = (const float*)d_in[3];
  const float* Wo = (const float*)d_in[4];
  float* out = (float*)d_out;

  char* ws = (char*)d_ws;
  u16* Xb  = (u16*)ws;                          // 16 MB
  u16* Wqb = (u16*)(ws + (size_t)16777216);     // 4 x 2 MB
  u16* Wkb = Wqb + 1048576;
  u16* Wvb = Wkb + 1048576;
  u16* Wob = Wvb + 1048576;
  u16* QKV = (u16*)(ws + (size_t)25165824);     // 3 x 16.78 MB
  u16* At  = (u16*)(ws + (size_t)75497472);     // 16 MB

  cvt_all<<<12288, 256, 0, stream>>>(x, Wq, Wk, Wv, Wo, Xb, Wqb, Wkb, Wvb, Wob);
  gemm_qkv<<<dim3(8, 64, 3), 256, 0, stream>>>(Xb, Wqb, Wkb, Wvb, QKV);
  attn_kernel<<<dim3(64, 16), 256, 0, stream>>>(QKV, At);
  gemm_out<<<dim3(8, 64), 256, 0, stream>>>(At, Wob, out);
}

// Round 7
// 277.048 us; speedup vs baseline: 1.2843x; 1.0279x over previous
//
#include <hip/hip_runtime.h>
#include <hip/hip_bf16.h>

typedef unsigned short u16;
typedef unsigned int   u32;
typedef __attribute__((ext_vector_type(8))) __bf16 bf16x8;
typedef __attribute__((ext_vector_type(2))) __bf16 bf16x2;
typedef __attribute__((ext_vector_type(8))) u16    ushort8v;
typedef __attribute__((ext_vector_type(4))) short  short4v;
typedef __attribute__((ext_vector_type(2))) float  f32x2;
typedef __attribute__((ext_vector_type(4))) float  floatx4;

#define EMBED 1024
#define SEQ   2048
#define BATCH 4
#define NH    16
#define DKH   64
#define BHN   (BATCH*NH)              // 64
#define ZSTRIDE ((size_t)BHN*SEQ*DKH) // elements per Q/K/V plane

// ---- fp32 -> bf16 RTNE ----
__device__ __forceinline__ u16 f2bf(float f){
  union { float f; unsigned u; } v; v.f = f;
  unsigned r = (v.u + 0x7FFFu + ((v.u >> 16) & 1u)) >> 16;
  return (u16)r;
}
// packed pair via v_cvt_pk_bf16_f32
__device__ __forceinline__ u32 pk2(float a, float b){
  f32x2 v = {a, b};
  return __builtin_bit_cast(u32, __builtin_convertvector(v, bf16x2));
}

__device__ __forceinline__ bf16x8 ld_frag(const u16* p){
  return __builtin_bit_cast(bf16x8, *(const ushort8v*)p);
}

__device__ __forceinline__ floatx4 mfma16(bf16x8 a, bf16x8 b, floatx4 c){
  return __builtin_amdgcn_mfma_f32_16x16x32_bf16(a, b, c, 0, 0, 0);
}
// K=16 MFMA: A/B are 4 bf16 (2 VGPRs) — P-in-registers PV path
__device__ __forceinline__ floatx4 mfma_pv(short4v a, short4v b, floatx4 c){
  return __builtin_amdgcn_mfma_f32_16x16x16bf16_1k(a, b, c, 0, 0, 0);
}

// async global->LDS, 16B per lane; LDS dst must be uniform_base + lane*16
__device__ __forceinline__ void gl_lds16(const u16* g, u16* l){
  __builtin_amdgcn_global_load_lds((const __attribute__((address_space(1))) void*)g,
                                   (__attribute__((address_space(3))) void*)l,
                                   16, 0, 0);
}

// =================== fused cast kernel ===================
__global__ __launch_bounds__(256) void cvt_all(const float* __restrict__ x,
    const float* __restrict__ wq, const float* __restrict__ wk,
    const float* __restrict__ wv, const float* __restrict__ wo,
    u16* __restrict__ Xb, u16* __restrict__ Wqb, u16* __restrict__ Wkb,
    u16* __restrict__ Wvb, u16* __restrict__ Wob){
  int b = blockIdx.x;
  const float* src; u16* dst; int i;
  if (b < 8192){ src = x; dst = Xb; i = b*256 + threadIdx.x; }
  else {
    int k = (b - 8192) >> 10, r = (b - 8192) & 1023;
    src = (k==0) ? wq : (k==1) ? wk : (k==2) ? wv : wo;
    dst = (k==0) ? Wqb : (k==1) ? Wkb : (k==2) ? Wvb : Wob;
    i = r*256 + threadIdx.x;
  }
  float4 v = ((const float4*)src)[i];
  ushort4 o;
  o.x = f2bf(v.x); o.y = f2bf(v.y); o.z = f2bf(v.z); o.w = f2bf(v.w);
  ((ushort4*)dst)[i] = o;
}

// ========== GEMM core: double-buffered DMA staging, ONE barrier per kt ==========
// C[128x128] = A[128xK] * B[128xK]^T, K=1024, bf16 in, fp32 acc.
// As/Bs are [2][128*32] double buffers (32 KB total).
__device__ __forceinline__ void gemm_core_db(const u16* Abase, const u16* Bbase,
                                             u16* As, u16* Bs, floatx4 acc[4][4]){
  const int tid  = threadIdx.x;
  const int lane = tid & 63, w = tid >> 6;
  const int lm   = lane & 15, quad = lane >> 4;
  const int wm   = (w & 1) * 64, wn = (w >> 1) * 64;
  const int row0 = tid >> 2, kc = tid & 3;        // staging coords (r=0)
  const int row1 = (256 + tid) >> 2;              // r=1 rows

  #pragma unroll
  for (int mi = 0; mi < 4; ++mi)
    #pragma unroll
    for (int ni = 0; ni < 4; ++ni)
      acc[mi][ni] = (floatx4){0.f, 0.f, 0.f, 0.f};

  // prologue: stage kt=0 into buffer 0
  gl_lds16(Abase + (size_t)row0*EMBED + kc*8, As + tid*8);
  gl_lds16(Bbase + (size_t)row0*EMBED + kc*8, Bs + tid*8);
  gl_lds16(Abase + (size_t)row1*EMBED + kc*8, As + (256 + tid)*8);
  gl_lds16(Bbase + (size_t)row1*EMBED + kc*8, Bs + (256 + tid)*8);

  for (int kt = 0; kt < EMBED/32; ++kt){
    const int cur = kt & 1;
    // one barrier: drains vmcnt (buf[cur] DMA done) + all waves finished
    // reading buf[cur^1] last iter -> safe to overwrite below.
    __syncthreads();
    if (kt + 1 < EMBED/32){
      const int k0 = (kt + 1) * 32;
      u16* Ad = As + (cur^1)*128*32;
      u16* Bd = Bs + (cur^1)*128*32;
      gl_lds16(Abase + (size_t)row0*EMBED + k0 + kc*8, Ad + tid*8);
      gl_lds16(Bbase + (size_t)row0*EMBED + k0 + kc*8, Bd + tid*8);
      gl_lds16(Abase + (size_t)row1*EMBED + k0 + kc*8, Ad + (256 + tid)*8);
      gl_lds16(Bbase + (size_t)row1*EMBED + k0 + kc*8, Bd + (256 + tid)*8);
    }
    const u16* Ac = As + cur*128*32;
    const u16* Bc = Bs + cur*128*32;
    bf16x8 af[4], bf[4];
    #pragma unroll
    for (int mi = 0; mi < 4; ++mi)
      af[mi] = ld_frag(&Ac[(wm + mi*16 + lm)*32 + quad*8]);
    #pragma unroll
    for (int ni = 0; ni < 4; ++ni)
      bf[ni] = ld_frag(&Bc[(wn + ni*16 + lm)*32 + quad*8]);
    #pragma unroll
    for (int mi = 0; mi < 4; ++mi)
      #pragma unroll
      for (int ni = 0; ni < 4; ++ni)
        acc[mi][ni] = mfma16(af[mi], bf[ni], acc[mi][ni]);
  }
}

// QKV projection. grid (64, 24): x = m-tile (XCD = x%8 -> all 24 (n,z) blocks
// of an m-tile share the XCD; the 256 KB X-tile stays L2-resident), y = n+8z.
// z=0: Q (scaled by 0.125*log2e), z=1: K — layout [bh][s][d].
// z=2: V — layout [bh][d][s] plain (attn XOR-swizzles at the DMA source).
#define QSCALE 0.1803368801111204f   // 0.125 * log2(e)
__global__ __launch_bounds__(256) void gemm_qkv(const u16* __restrict__ X,
    const u16* __restrict__ Wq, const u16* __restrict__ Wk, const u16* __restrict__ Wv,
    u16* __restrict__ QKV){
  __shared__ __attribute__((aligned(16))) u16 As[2*128*32];
  __shared__ __attribute__((aligned(16))) u16 Bs[2*128*32];
  const int z  = blockIdx.y >> 3;
  const u16* W = (z == 0) ? Wq : (z == 1) ? Wk : Wv;
  const int m0 = blockIdx.x * 128, n0 = (blockIdx.y & 7) * 128;
  floatx4 acc[4][4];
  gemm_core_db(X + (size_t)m0*EMBED, W + (size_t)n0*EMBED, As, Bs, acc);

  const int tid = threadIdx.x, lane = tid & 63, w = tid >> 6;
  const int lm = lane & 15, quad = lane >> 4;
  const int wm = (w & 1) * 64, wn = (w >> 1) * 64;
  u16* outz = QKV + (size_t)z * ZSTRIDE;

  if (z == 2){
    #pragma unroll
    for (int mi = 0; mi < 4; ++mi)
      #pragma unroll
      for (int ni = 0; ni < 4; ++ni){
        int mbase = m0 + wm + mi*16 + quad*4;       // 4 consecutive s
        int n = n0 + wn + ni*16 + lm;
        int b = mbase >> 11, sb = mbase & 2047;
        int h = n >> 6, d = n & 63;
        u16* dst = outz + (((size_t)(b*NH + h))*DKH + d)*SEQ + sb;
        uint2 pv;
        pv.x = pk2(acc[mi][ni][0], acc[mi][ni][1]);
        pv.y = pk2(acc[mi][ni][2], acc[mi][ni][3]);
        *reinterpret_cast<uint2*>(dst) = pv;
      }
  } else {
    const float scale = (z == 0) ? QSCALE : 1.0f;
    #pragma unroll
    for (int mi = 0; mi < 4; ++mi)
      #pragma unroll
      for (int ni = 0; ni < 4; ++ni)
        #pragma unroll
        for (int r = 0; r < 4; ++r){
          int m = m0 + wm + mi*16 + quad*4 + r;
          int n = n0 + wn + ni*16 + lm;
          int b = m >> 11, s = m & 2047, h = n >> 6, d = n & 63;
          outz[(((size_t)(b*NH + h))*SEQ + s)*DKH + d] = f2bf(acc[mi][ni][r] * scale);
        }
  }
}

// Final: out = Attn * Wo^T, fp32 out [b*s][e]. grid (64, 8): x = m-tile.
__global__ __launch_bounds__(256) void gemm_out(const u16* __restrict__ A,
    const u16* __restrict__ W, float* __restrict__ C){
  __shared__ __attribute__((aligned(16))) u16 As[2*128*32];
  __shared__ __attribute__((aligned(16))) u16 Bs[2*128*32];
  const int m0 = blockIdx.x * 128, n0 = blockIdx.y * 128;
  floatx4 acc[4][4];
  gemm_core_db(A + (size_t)m0*EMBED, W + (size_t)n0*EMBED, As, Bs, acc);

  const int tid = threadIdx.x, lane = tid & 63, w = tid >> 6;
  const int lm = lane & 15, quad = lane >> 4;
  const int wm = (w & 1) * 64, wn = (w >> 1) * 64;
  #pragma unroll
  for (int mi = 0; mi < 4; ++mi)
    #pragma unroll
    for (int ni = 0; ni < 4; ++ni)
      #pragma unroll
      for (int r = 0; r < 4; ++r){
        int m = m0 + wm + mi*16 + quad*4 + r;
        int n = n0 + wn + ni*16 + lm;
        C[(size_t)m*EMBED + n] = acc[mi][ni][r];
      }
}

// =================== fused attention (P stays in registers) ===================
// grid (64, 16): x = bh (XCD-local L2 reuse of K/V), y = q-block of 128 rows.
// 4 waves x 32 q (2 q-tiles). Keys chunked by 64, K/V double-buffered DMA,
// single barrier per kt. S^T C-layout (q=lm, key=quad*4+reg) is EXACTLY the
// A-operand layout of mfma_f32_16x16x16_bf16 -> exp'd P packs straight into
// PV A-frags: no P LDS round-trip, no fence. V staged [d][key] stride 64 with
// XOR swizzle (g^(d&7)) applied at the DMA *source* so b64 B-frag reads are
// conflict-free while DMA dst stays linear. LDS = 33 KB -> 4 blocks/CU.
#define KSS 520
__global__ __launch_bounds__(256, 4) void attn_kernel(const u16* __restrict__ QKV,
                                                      u16* __restrict__ Out){
  __shared__ __attribute__((aligned(16))) u16 Ks[2][8*KSS];   // 16.6 KB
  __shared__ __attribute__((aligned(16))) u16 Vs[2][64*64];   // 16.4 KB

  const int tid = threadIdx.x, lane = tid & 63, w = tid >> 6;
  const int lm = lane & 15, quad = lane >> 4;
  const int bh = blockIdx.x;
  const int q0 = blockIdx.y * 128;
  const u16* Qh = QKV + (size_t)bh * SEQ * DKH;
  const u16* Kh = QKV + ZSTRIDE + (size_t)bh * SEQ * DKH;
  const u16* Vh = QKV + 2*ZSTRIDE + (size_t)bh * DKH * SEQ;  // [d][s] plain

  // K staging coords (chunk c = r*4 + cK is wave-uniform)
  const int sK = tid & 63, cK = tid >> 6;
  // V staging coords: i = r*256+tid -> d = i>>3 (r=1: d+32), group g = i&7.
  // XOR swizzle at source: src key-group = g ^ (d&7); (d+32)&7 == d&7.
  const int dV = tid >> 3, gV = tid & 7;
  const size_t vsrc0 = (size_t)dV * SEQ + ((gV ^ (dV & 7)) * 8);
  const size_t vsrc1 = vsrc0 + (size_t)32 * SEQ;

  // Q fragments: B-operand layout (n=q, k=d contiguous)
  bf16x8 qf[2][2];
  #pragma unroll
  for (int qt = 0; qt < 2; ++qt)
    #pragma unroll
    for (int st = 0; st < 2; ++st)
      qf[qt][st] = ld_frag(Qh + (size_t)(q0 + w*32 + qt*16 + lm)*DKH + st*32 + quad*8);

  const short4v ones4 = {0x3F80, 0x3F80, 0x3F80, 0x3F80};   // bf16 1.0 x4

  floatx4 o[2][4], lac[2];
  #pragma unroll
  for (int qt = 0; qt < 2; ++qt){
    lac[qt] = (floatx4){0.f, 0.f, 0.f, 0.f};
    #pragma unroll
    for (int dt = 0; dt < 4; ++dt) o[qt][dt] = (floatx4){0.f, 0.f, 0.f, 0.f};
  }

  // prologue: stage kt=0 into buffer 0
  gl_lds16(Kh + (size_t)sK*DKH + cK*8,     Ks[0] + cK*KSS + sK*8);
  gl_lds16(Kh + (size_t)sK*DKH + (cK+4)*8, Ks[0] + (cK+4)*KSS + sK*8);
  gl_lds16(Vh + vsrc0,                     Vs[0] + tid*8);
  gl_lds16(Vh + vsrc1,                     Vs[0] + 2048 + tid*8);

  for (int kt = 0; kt < SEQ/64; ++kt){
    const int cur = kt & 1;
    // one barrier per kt: drains vmcnt (buf[cur] DMA done) + all waves done
    // reading buf[cur^1] in iter kt-1 -> safe to overwrite below.
    __syncthreads();
    if (kt + 1 < SEQ/64){
      const int nk0 = (kt + 1) * 64;
      gl_lds16(Kh + (size_t)(nk0 + sK)*DKH + cK*8,     Ks[cur^1] + cK*KSS + sK*8);
      gl_lds16(Kh + (size_t)(nk0 + sK)*DKH + (cK+4)*8, Ks[cur^1] + (cK+4)*KSS + sK*8);
      gl_lds16(Vh + vsrc0 + nk0,                       Vs[cur^1] + tid*8);
      gl_lds16(Vh + vsrc1 + nk0,                       Vs[cur^1] + 2048 + tid*8);
    }
    const u16* Kc = Ks[cur];
    const u16* Vc = Vs[cur];

    #pragma unroll
    for (int t = 0; t < 4; ++t){
      // S^T tile t: A=K (m=key t*16+lm fragment rows), B=Q (n=q)
      bf16x8 kf0 = ld_frag(&Kc[quad*KSS     + (t*16 + lm)*8]);
      bf16x8 kf1 = ld_frag(&Kc[(quad+4)*KSS + (t*16 + lm)*8]);
      short4v pf[2];
      #pragma unroll
      for (int qt = 0; qt < 2; ++qt){
        floatx4 s = (floatx4){0.f,0.f,0.f,0.f};
        s = mfma16(kf0, qf[qt][0], s);
        s = mfma16(kf1, qf[qt][1], s);
        uint2 p;
        p.x = pk2(__builtin_amdgcn_exp2f(s[0]), __builtin_amdgcn_exp2f(s[1]));
        p.y = pk2(__builtin_amdgcn_exp2f(s[2]), __builtin_amdgcn_exp2f(s[3]));
        pf[qt] = __builtin_bit_cast(short4v, p);   // A-frag: m=q(lm), k=key(quad*4+j)
      }
      // l += P·1
      lac[0] = mfma_pv(pf[0], ones4, lac[0]);
      lac[1] = mfma_pv(pf[1], ones4, lac[1]);
      // O += P·V : B-frag from swizzled Vs, b64 per (t,dt)
      const int cg = ((t*2 + (quad >> 1)) ^ (lm & 7)) * 8 + (quad & 1) * 4;
      #pragma unroll
      for (int dt = 0; dt < 4; ++dt){
        short4v vb = __builtin_bit_cast(short4v,
                        *(const uint2*)(Vc + (dt*16 + lm)*64 + cg));
        o[0][dt] = mfma_pv(pf[0], vb, o[0][dt]);
        o[1][dt] = mfma_pv(pf[1], vb, o[1][dt]);
      }
    }
  }

  const int bI = bh >> 4, h = bh & 15;
  #pragma unroll
  for (int qt = 0; qt < 2; ++qt){
    floatx4 inv;
    #pragma unroll
    for (int r = 0; r < 4; ++r) inv[r] = __builtin_amdgcn_rcpf(lac[qt][r]);
    #pragma unroll
    for (int dt = 0; dt < 4; ++dt)
      #pragma unroll
      for (int r = 0; r < 4; ++r){
        int s = q0 + w*32 + qt*16 + quad*4 + r;
        Out[((size_t)(bI*SEQ + s))*EMBED + h*DKH + dt*16 + lm] = f2bf(o[qt][dt][r] * inv[r]);
      }
  }
}

// =================== launch ===================
extern "C" void kernel_launch(void* const* d_in, const int* in_sizes, int n_in,
                              void* d_out, int out_size, void* d_ws, size_t ws_size,
                              hipStream_t stream){
  const float* x  = (const float*)d_in[0];
  const float* Wq = (const float*)d_in[1];
  const float* Wk = (const float*)d_in[2];
  const float* Wv = (const float*)d_in[3];
  const float* Wo = (const float*)d_in[4];
  float* out = (float*)d_out;

  char* ws = (char*)d_ws;
  u16* Xb  = (u16*)ws;                          // 16 MB
  u16* Wqb = (u16*)(ws + (size_t)16777216);     // 4 x 2 MB
  u16* Wkb = Wqb + 1048576;
  u16* Wvb = Wkb + 1048576;
  u16* Wob = Wvb + 1048576;
  u16* QKV = (u16*)(ws + (size_t)25165824);     // 3 x 16.78 MB
  u16* At  = (u16*)(ws + (size_t)75497472);     // 16 MB

  cvt_all<<<12288, 256, 0, stream>>>(x, Wq, Wk, Wv, Wo, Xb, Wqb, Wkb, Wvb, Wob);
  gemm_qkv<<<dim3(64, 24), 256, 0, stream>>>(Xb, Wqb, Wkb, Wvb, QKV);
  attn_kernel<<<dim3(64, 16), 256, 0, stream>>>(QKV, At);
  gemm_out<<<dim3(64, 8), 256, 0, stream>>>(At, Wob, out);
}